// Round 20
// baseline (182.831 us; speedup 1.0000x reference)
//
#include <hip/hip_runtime.h>

// SharedVectorQuantizer forward, MI355X. x:[65536,128]f32 cb:[4096,128]f32
// out: tokens[M] (float) | quantized[M*128] | vq_loss[1]
//
// k_pre   : fused np ||x||^2 (4-lane-split np-exact tree, verified r18),
//           np ||e||^2 (+bf16 hi/lo), codebook->bf16-hi frag prep,
//           counter zeroing, out_loss zero. Grid 1024x256.
// k_big   : r16-verified body; r20: 3-way chunk split (grid 768 = exactly
//           3 blocks/CU; r15's 2-way split left the 512-block grid capping
//           residency at 2 blocks/CU -> pipes serialized, occupancy 18.5%).
// k_cand  : chunks within dlt of row best -> sub-bucketed lists. dlt=8e-3.
// k_exact : np-bit-exact fp32 chain rescore of candidates, u64 atomicMin.
// k_gather: keys -> token + gather quantized + per-block MSE partials.
// k_loss  : 32 blocks, one atomicAdd each into out_loss (zeroed in k_pre).
//
// Big scratch lives in the quantized-output region (dead before k_gather).

#define D_ 128
#define MROWS 65536
#define KCODES 4096
#define NSUB 16
#define SUBCAP 512

// float offsets within out_q scratch region (8388608 floats)
// cm occupies [0, 64*65536) = [0, 4194304)
#define OQ_AH    4194304   // 64 chunks * 1024 units * 16B bf16-hi frags
#define OQ_PAIRS 4587520   // int[64*NSUB*SUBCAP] = 524288
#define OQ_T1    5111808   // f32[65536]
#define OQ_T3    5177344   // f32[4096]
#define OQ_CNT   5181440   // int[64*NSUB*16] (each counter on its own 64B line)
#define OQ_T3HL  5197824   // u32[4096] packed t3h | t3l<<16

typedef __attribute__((ext_vector_type(8))) short bf16x8;
typedef __attribute__((ext_vector_type(16))) float f32x16;

__device__ __forceinline__ unsigned short bf16rne(float f) {
  unsigned u = __float_as_uint(f);
  unsigned r = (u + 0x7FFFu + ((u >> 16) & 1u)) >> 16;
  return (unsigned short)r;
}
__device__ __forceinline__ float bf16tof(unsigned short h) {
  return __uint_as_float(((unsigned)h) << 16);
}

__device__ __forceinline__ void gload_lds16(const void* g, void* l) {
  __builtin_amdgcn_global_load_lds(
      (const __attribute__((address_space(1))) unsigned int*)g,
      (__attribute__((address_space(3))) unsigned int*)l, 16, 0, 0);
}

__device__ __forceinline__ float4 f4add(float4 a, float4 b) {
  return make_float4(a.x + b.x, a.y + b.y, a.z + b.z, a.w + b.w);
}
__device__ __forceinline__ float4 f4sq(float4 v) {
  return make_float4(v.x * v.x, v.y * v.y, v.z * v.z, v.w * v.w);
}

// numpy fp32 pairwise sum of squares, AVX-512 npyv path (verified round 3)
__device__ __forceinline__ float np_sumsq_row(const float4* __restrict__ r) {
  float4 W[4];
#pragma unroll
  for (int a = 0; a < 4; ++a) {
    float4 c0 = f4sq(r[0 * 4 + a]), c1 = f4sq(r[1 * 4 + a]);
    float4 c2 = f4sq(r[2 * 4 + a]), c3 = f4sq(r[3 * 4 + a]);
    float4 c4 = f4sq(r[4 * 4 + a]), c5 = f4sq(r[5 * 4 + a]);
    float4 c6 = f4sq(r[6 * 4 + a]), c7 = f4sq(r[7 * 4 + a]);
    W[a] = f4add(f4add(f4add(c0, c1), f4add(c2, c3)),
                 f4add(f4add(c4, c5), f4add(c6, c7)));
  }
  float4 U0 = f4add(W[0], W[2]);
  float4 U1 = f4add(W[1], W[3]);
  float4 T = f4add(U0, U1);
  float s0 = T.x + T.z, s1 = T.y + T.w;
  return s0 + s1;
}

// Fused prologue, grid 1024 x 256. t1 via 4-lane-split np tree (verified
// bit-exact on HW in r18). prep unit gid<65536, t3/t3hl gid<4096,
// cnt gid<16384, out_loss gid==0.
__global__ __launch_bounds__(256, 2)
void k_pre(const float* __restrict__ x, const float* __restrict__ cb,
           float* __restrict__ outq, float* __restrict__ out_loss) {
  int gid = blockIdx.x * 256 + threadIdx.x;
  float* t1 = outq + OQ_T1;
  float* t3 = outq + OQ_T3;
  unsigned* t3hl = (unsigned*)(outq + OQ_T3HL);
  int* cnt = (int*)(outq + OQ_CNT);

  // ---- t1, 4-lane split (all 262144 threads; 4 lanes per row) ----
  {
    int row = gid >> 2, a = gid & 3;
    const float4* r4 = (const float4*)(x + (size_t)row * D_);
    float4 c0 = f4sq(r4[0 * 4 + a]), c1 = f4sq(r4[1 * 4 + a]);
    float4 c2 = f4sq(r4[2 * 4 + a]), c3 = f4sq(r4[3 * 4 + a]);
    float4 c4 = f4sq(r4[4 * 4 + a]), c5 = f4sq(r4[5 * 4 + a]);
    float4 c6 = f4sq(r4[6 * 4 + a]), c7 = f4sq(r4[7 * 4 + a]);
    float4 wv = f4add(f4add(f4add(c0, c1), f4add(c2, c3)),
                      f4add(f4add(c4, c5), f4add(c6, c7)));   // == W[a]
    int lb = (threadIdx.x & 63) & ~3;
    int sp = lb + (a | 2);
    float4 wp;
    wp.x = __shfl(wv.x, sp, 64); wp.y = __shfl(wv.y, sp, 64);
    wp.z = __shfl(wv.z, sp, 64); wp.w = __shfl(wv.w, sp, 64);
    float4 U = f4add(wv, wp);
    float4 u1;
    u1.x = __shfl(U.x, lb + 1, 64); u1.y = __shfl(U.y, lb + 1, 64);
    u1.z = __shfl(U.z, lb + 1, 64); u1.w = __shfl(U.w, lb + 1, 64);
    float4 T = f4add(U, u1);
    float res = (T.x + T.z) + (T.y + T.w);
    if (a == 0) t1[row] = res;
  }

  if (gid < KCODES) {
    float s = np_sumsq_row((const float4*)(cb + (size_t)gid * D_));
    t3[gid] = s;
    unsigned short h = bf16rne(s);
    unsigned short l = bf16rne(s - bf16tof(h));
    t3hl[gid] = (unsigned)h | ((unsigned)l << 16);
  }
  if (gid < 64 * NSUB * 16) cnt[gid] = 0;
  if (gid == 0) out_loss[0] = 0.f;

  if (gid < 64 * 1024) {
    // prep unit u: ch=u>>10, s=(u&1023)>>6 (kt=s>>1, ct=s&1), p=u&63
    // (kg=p>>5, nl=p&31); code = ch*64+ct*32+nl, k-off = (kt*2+kg)*8.
    int u = gid;
    int ch = u >> 10, r = u & 1023;
    int s2 = r >> 6, p = r & 63;
    int kt = s2 >> 1, ct = s2 & 1;
    int kg = p >> 5, nl = p & 31;
    int code = ch * 64 + ct * 32 + nl;
    const float* src = cb + (size_t)code * D_ + (kt * 2 + kg) * 8;
    bf16x8 h8;
#pragma unroll
    for (int e = 0; e < 8; ++e) h8[e] = (short)bf16rne(src[e]);
    *(bf16x8*)((char*)(outq + OQ_AH) + (size_t)u * 16) = h8;
  }
}

// Filter sweep (r16-verified body). Block = 256 thr = 4 waves; wave =
// 64 rows (xt=2) x 64-code chunks. r20: grid = 256 row-groups x 3 chunk
// splits (21/21/22 chunks) = 768 blocks = exactly 3 blocks/CU resident.
// acc = xh*eh - t3/2 (slab MFMA). Per iter: 16 ds_read_b128 -> 32 MFMA +
// 4 slab MFMA. cm store AFTER barrier; t3hl prefetched 1 iter ahead.
__global__ __launch_bounds__(256, 3)
void k_big(const float* __restrict__ x, const unsigned* __restrict__ t3hl,
           float* __restrict__ outq) {
  __shared__ char lds[2][16384];
  const int tid = threadIdx.x;
  const int lane = tid & 63;
  const int w = tid >> 6;
  const int kg = lane >> 5, nl = lane & 31;
  const int rb = blockIdx.x / 3, cs = blockIdx.x % 3;
  const int c0 = (cs * 64) / 3;        // 0, 21, 42
  const int c1 = ((cs + 1) * 64) / 3;  // 21, 42, 64
  const int row0 = rb * 256 + w * 64;

  const char* AhB = (const char*)(outq + OQ_AH);
  float* cm = outq;   // [64][65536]

  // x-hi fragments: lane holds row row0+xt*32+nl, k = (kt*2+kg)*8 + e
  bf16x8 xh[2][8];
#pragma unroll
  for (int xt = 0; xt < 2; ++xt)
#pragma unroll
    for (int kt = 0; kt < 8; ++kt) {
      const float* src =
          x + (size_t)(row0 + xt * 32 + nl) * D_ + (kt * 2 + kg) * 8;
      float f[8];
      *(float4*)(f) = *(const float4*)(src);
      *(float4*)(f + 4) = *(const float4*)(src + 4);
      bf16x8 h;
#pragma unroll
      for (int e = 0; e < 8; ++e) h[e] = (short)bf16rne(f[e]);
      xh[xt][kt] = h;
    }

  // B frag for t3 slab: k=0,1 hold -0.5 (kg==0 lanes)
  bf16x8 bneg = 0;
  if (kg == 0) { bneg[0] = (short)0xBF00; bneg[1] = (short)0xBF00; }

#define STAGE(c, buf)                                                         \
  {                                                                           \
    const char* sAh = AhB + (size_t)(c) * 16384;                              \
    _Pragma("unroll")                                                         \
    for (int i4 = 0; i4 < 4; ++i4) {                                          \
      int ub = i4 * 256 + w * 64;                                             \
      gload_lds16(sAh + (size_t)(ub + lane) * 16, (buf) + ub * 16);           \
    }                                                                         \
  }

  STAGE(c0, lds[0]);
  unsigned v0 = t3hl[c0 * 64 + nl];
  unsigned v1 = t3hl[c0 * 64 + 32 + nl];
  __syncthreads();

  int b = 0;
  for (int ch = c0; ch < c1; ++ch) {
    char* cur = lds[b];
    if (ch + 1 < c1) STAGE(ch + 1, lds[b ^ 1]);

    unsigned nv0 = 0, nv1 = 0;
    if (ch + 1 < c1) {
      nv0 = t3hl[(ch + 1) * 64 + nl];
      nv1 = t3hl[(ch + 1) * 64 + 32 + nl];
    }

    bf16x8 s0 = 0, s1 = 0;
    if (kg == 0) {
      s0[0] = (short)(v0 & 0xFFFFu); s0[1] = (short)(v0 >> 16);
      s1[0] = (short)(v1 & 0xFFFFu); s1[1] = (short)(v1 >> 16);
    }

    f32x16 a00 = 0, a01 = 0, a10 = 0, a11 = 0;
    a00 = __builtin_amdgcn_mfma_f32_32x32x16_bf16(s0, bneg, a00, 0, 0, 0);
    a01 = __builtin_amdgcn_mfma_f32_32x32x16_bf16(s0, bneg, a01, 0, 0, 0);
    a10 = __builtin_amdgcn_mfma_f32_32x32x16_bf16(s1, bneg, a10, 0, 0, 0);
    a11 = __builtin_amdgcn_mfma_f32_32x32x16_bf16(s1, bneg, a11, 0, 0, 0);
#pragma unroll
    for (int kt = 0; kt < 8; ++kt) {
      bf16x8 e0 = *(const bf16x8*)(cur + ((kt * 2 + 0) * 64 + lane) * 16);
      bf16x8 e1 = *(const bf16x8*)(cur + ((kt * 2 + 1) * 64 + lane) * 16);
      a00 = __builtin_amdgcn_mfma_f32_32x32x16_bf16(e0, xh[0][kt], a00, 0, 0, 0);
      a01 = __builtin_amdgcn_mfma_f32_32x32x16_bf16(e0, xh[1][kt], a01, 0, 0, 0);
      a10 = __builtin_amdgcn_mfma_f32_32x32x16_bf16(e1, xh[0][kt], a10, 0, 0, 0);
      a11 = __builtin_amdgcn_mfma_f32_32x32x16_bf16(e1, xh[1][kt], a11, 0, 0, 0);
    }

    float m0 = -3.4e38f, m1 = -3.4e38f;
#pragma unroll
    for (int e = 0; e < 16; ++e) {
      m0 = fmaxf(m0, fmaxf(a00[e], a10[e]));   // xt0 rows
      m1 = fmaxf(m1, fmaxf(a01[e], a11[e]));   // xt1 rows
    }
    m0 = fmaxf(m0, __shfl_xor(m0, 32, 64));
    m1 = fmaxf(m1, __shfl_xor(m1, 32, 64));
    float mv = (kg == 0) ? m0 : m1;            // lanes 0-31: xt0, 32-63: xt1
    size_t caddr = (size_t)ch * MROWS + row0 + kg * 32 + nl;

    __syncthreads();
    cm[caddr] = mv;     // store after barrier: drains at NEXT barrier
    v0 = nv0; v1 = nv1;
    b ^= 1;
  }
#undef STAGE
}

// Candidate select, tile form. Sub-bucketed counters (round 7 verified).
__global__ __launch_bounds__(256, 4)
void k_cand(const float* __restrict__ cm, int* __restrict__ cnt,
            int* __restrict__ pairs, unsigned long long* __restrict__ keys,
            float dlt) {
  __shared__ float wmax[4][64];
  __shared__ float thrs[64];
  const int tid = threadIdx.x, lane = tid & 63, w = tid >> 6;
  const int r = blockIdx.x * 64 + lane;
  const int sub = blockIdx.x & (NSUB - 1);
  float v[16];
#pragma unroll
  for (int i = 0; i < 16; ++i) v[i] = cm[(size_t)(w * 16 + i) * MROWS + r];
  float m = v[0];
#pragma unroll
  for (int i = 1; i < 16; ++i) m = fmaxf(m, v[i]);
  wmax[w][lane] = m;
  __syncthreads();
  if (w == 0) {
    float A = fmaxf(fmaxf(wmax[0][lane], wmax[1][lane]),
                    fmaxf(wmax[2][lane], wmax[3][lane]));
    thrs[lane] = A - dlt;
    keys[r] = ~0ull;
  }
  __syncthreads();
  float thr = thrs[lane];
#pragma unroll
  for (int i = 0; i < 16; ++i) {
    if (v[i] >= thr) {
      int ch = w * 16 + i;
      int slot = ch * NSUB + sub;
      int s = atomicAdd(cnt + slot * 16, 1);
      if (s < SUBCAP) pairs[slot * SUBCAP + s] = r;
    }
  }
}

// np-bit-exact rescore. Block = (chunk ch, sub-bucket).
__global__ __launch_bounds__(256, 4)
void k_exact(const float* __restrict__ x, const float* __restrict__ cb,
             const int* __restrict__ cnt, const int* __restrict__ pairs,
             const float* __restrict__ t1, const float* __restrict__ t3,
             unsigned long long* __restrict__ keys) {
  __shared__ float elds[32 * 65 * 4];
  __shared__ float xlds[4][D_];
  int ch = blockIdx.x >> 4, sub = blockIdx.x & (NSUB - 1);
  int tid = threadIdx.x, lane = tid & 63, wid = tid >> 6;
#pragma unroll
  for (int it2 = 0; it2 < 8; ++it2) {
    int u = it2 * 256 + tid;        // 0..2047
    int c = u >> 5, d4 = u & 31;
    float4 v = *(const float4*)(cb + ((size_t)ch * 64 + c) * D_ + d4 * 4);
    *(float4*)(elds + (d4 * 65 + c) * 4) = v;
  }
  float t3v = t3[ch * 64 + lane];
  __syncthreads();
  int slot = ch * NSUB + sub;
  int n = cnt[slot * 16]; if (n > SUBCAP) n = SUBCAP;
  const int* lst = pairs + slot * SUBCAP;
  for (int idx = wid; idx < n; idx += 4) {
    int row = lst[idx];
    *(float2*)(&xlds[wid][lane * 2]) = *(const float2*)(x + (size_t)row * D_ + lane * 2);
    asm volatile("s_waitcnt lgkmcnt(0)" ::: "memory");
    float acc = 0.f;
    float t1r = t1[row];
#pragma unroll 8
    for (int d4 = 0; d4 < 32; ++d4) {
      float4 xv = *(const float4*)(&xlds[wid][d4 * 4]);
      float4 ev = *(const float4*)(elds + (d4 * 65 + lane) * 4);
      acc = __builtin_fmaf(xv.x, ev.x, acc);
      acc = __builtin_fmaf(xv.y, ev.y, acc);
      acc = __builtin_fmaf(xv.z, ev.z, acc);
      acc = __builtin_fmaf(xv.w, ev.w, acc);
    }
    float s = __builtin_fmaf(-2.f, acc, t1r) + t3v;
    unsigned u32 = __float_as_uint(s);
    u32 = u32 ^ (unsigned)(((int)u32 >> 31) | 0x80000000);
    unsigned long long key =
        ((unsigned long long)u32 << 12) | (unsigned)(ch * 64 + lane);
#pragma unroll
    for (int off = 1; off < 64; off <<= 1) {
      unsigned long long o = __shfl_xor(key, off, 64);
      key = o < key ? o : key;
    }
    if (lane == 0) atomicMin(keys + row, key);
  }
}

// keys -> token + gather quantized + per-block MSE partials (no fences,
// no cross-block protocol -- r18 lesson). keys live in d_ws.
__global__ __launch_bounds__(256, 8)
void k_gather(const float* __restrict__ x, const float* __restrict__ cb,
              const unsigned long long* __restrict__ keys,
              float* __restrict__ tok_f, float* __restrict__ outq,
              float* __restrict__ partial) {
  int idx = blockIdx.x * 256 + threadIdx.x;
  int row = idx >> 5;
  int d4 = idx & 31;
  int t = (int)(keys[row] & 0xFFFull);
  if (d4 == 0) tok_f[row] = (float)t;
  float4 q = ((const float4*)(cb + (size_t)t * D_))[d4];
  float4 xv = ((const float4*)x)[idx];
  ((float4*)outq)[idx] = q;
  float dx = q.x - xv.x, dy = q.y - xv.y, dz = q.z - xv.z, dw = q.w - xv.w;
  float s = dx * dx + dy * dy + dz * dz + dw * dw;
#pragma unroll
  for (int off = 1; off < 64; off <<= 1) s += __shfl_xor(s, off, 64);
  __shared__ float red[4];
  int lane = threadIdx.x & 63, w = threadIdx.x >> 6;
  if (lane == 0) red[w] = s;
  __syncthreads();
  if (threadIdx.x == 0)
    partial[blockIdx.x] = red[0] + red[1] + red[2] + red[3];
}

// 32 blocks x 256 partials each; one atomicAdd per block into out_loss
// (zeroed by k_pre). Verified r13-r16.
__global__ __launch_bounds__(256, 1)
void k_loss(const float* __restrict__ partial, float* __restrict__ out_loss,
            float scale) {
  int i = blockIdx.x * 256 + threadIdx.x;
  float s = partial[i];
#pragma unroll
  for (int off = 1; off < 64; off <<= 1) s += __shfl_xor(s, off, 64);
  __shared__ float red[4];
  int lane = threadIdx.x & 63, w = threadIdx.x >> 6;
  if (lane == 0) red[w] = s;
  __syncthreads();
  if (threadIdx.x == 0)
    atomicAdd(out_loss, (red[0] + red[1] + red[2] + red[3]) * scale);
}

extern "C" void kernel_launch(void* const* d_in, const int* in_sizes, int n_in,
                              void* d_out, int out_size, void* d_ws, size_t ws_size,
                              hipStream_t stream) {
  const float* x = (const float*)d_in[0];
  const float* cb = (const float*)d_in[1];

  float* out_tok = (float*)d_out;
  float* outq = (float*)d_out + MROWS;
  float* out_loss = (float*)d_out + MROWS + (size_t)MROWS * D_;

  // ws: keys u64[65536] (512KB) | part f32[8192] (32KB)
  unsigned long long* keys = (unsigned long long*)d_ws;
  float* part = (float*)((char*)d_ws + 524288);

  float* t3 = outq + OQ_T3;
  float* t1 = outq + OQ_T1;
  unsigned* t3hl = (unsigned*)(outq + OQ_T3HL);
  int* cnt = (int*)(outq + OQ_CNT);
  int* pairs = (int*)(outq + OQ_PAIRS);

  k_pre<<<1024, 256, 0, stream>>>(x, cb, outq, out_loss);
  k_big<<<256 * 3, 256, 0, stream>>>(x, t3hl, outq);
  k_cand<<<MROWS / 64, 256, 0, stream>>>(outq, cnt, pairs, keys, 8e-3f);
  k_exact<<<64 * NSUB, 256, 0, stream>>>(x, cb, cnt, pairs, t1, t3, keys);
  const int gB = (MROWS * (D_ / 4)) / 256;   // 8192
  k_gather<<<gB, 256, 0, stream>>>(x, cb, keys, out_tok, outq, part);
  k_loss<<<32, 256, 0, stream>>>(part, out_loss,
                                 1.5f / (float)((size_t)MROWS * D_));
}

// Round 21
// 180.434 us; speedup vs baseline: 1.0133x; 1.0133x over previous
//
#include <hip/hip_runtime.h>

// SharedVectorQuantizer forward, MI355X. x:[65536,128]f32 cb:[4096,128]f32
// out: tokens[M] (float) | quantized[M*128] | vq_loss[1]
//
// VERIFIED BEST (r19, 181.2 us). Restored after r20's 3-way-split
// regression (occupancy up but prologue-repeat cost won: 77.4->79.9 us).
//
// k_pre   : fused np ||x||^2 (4-lane-split np-exact tree, verified r18),
//           np ||e||^2 (+bf16 hi/lo), codebook->bf16-hi frag prep,
//           counter zeroing, out_loss zero. Grid 1024x256.
// k_big   : 1-pass bf16-hi MFMA filter, wave = 64 rows (xt=2) x 64-code
//           chunks, -t3/2 via t3hl slab MFMA, 2-way chunk split,
//           cm store after barrier, t3hl prefetch 1 ahead.
// k_cand  : chunks within dlt of row best -> sub-bucketed lists. dlt=8e-3.
// k_exact : np-bit-exact fp32 chain rescore of candidates, u64 atomicMin.
// k_gather: keys -> token + gather quantized + per-block MSE partials.
// k_loss  : 32 blocks, one atomicAdd each into out_loss (zeroed in k_pre).
//
// Structure-plateau notes (r13-r20): counted-vmcnt neutral (r17),
// 3-blocks/CU grid split negative (r20), acc-split negative (r14),
// (256,4) VGPR cap spills (r12), device-fence fusion catastrophic (r18).
// Big scratch lives in the quantized-output region (dead before k_gather).

#define D_ 128
#define MROWS 65536
#define KCODES 4096
#define NSUB 16
#define SUBCAP 512

// float offsets within out_q scratch region (8388608 floats)
// cm occupies [0, 64*65536) = [0, 4194304)
#define OQ_AH    4194304   // 64 chunks * 1024 units * 16B bf16-hi frags
#define OQ_PAIRS 4587520   // int[64*NSUB*SUBCAP] = 524288
#define OQ_T1    5111808   // f32[65536]
#define OQ_T3    5177344   // f32[4096]
#define OQ_CNT   5181440   // int[64*NSUB*16] (each counter on its own 64B line)
#define OQ_T3HL  5197824   // u32[4096] packed t3h | t3l<<16

typedef __attribute__((ext_vector_type(8))) short bf16x8;
typedef __attribute__((ext_vector_type(16))) float f32x16;

__device__ __forceinline__ unsigned short bf16rne(float f) {
  unsigned u = __float_as_uint(f);
  unsigned r = (u + 0x7FFFu + ((u >> 16) & 1u)) >> 16;
  return (unsigned short)r;
}
__device__ __forceinline__ float bf16tof(unsigned short h) {
  return __uint_as_float(((unsigned)h) << 16);
}

__device__ __forceinline__ void gload_lds16(const void* g, void* l) {
  __builtin_amdgcn_global_load_lds(
      (const __attribute__((address_space(1))) unsigned int*)g,
      (__attribute__((address_space(3))) unsigned int*)l, 16, 0, 0);
}

__device__ __forceinline__ float4 f4add(float4 a, float4 b) {
  return make_float4(a.x + b.x, a.y + b.y, a.z + b.z, a.w + b.w);
}
__device__ __forceinline__ float4 f4sq(float4 v) {
  return make_float4(v.x * v.x, v.y * v.y, v.z * v.z, v.w * v.w);
}

// numpy fp32 pairwise sum of squares, AVX-512 npyv path (verified round 3)
__device__ __forceinline__ float np_sumsq_row(const float4* __restrict__ r) {
  float4 W[4];
#pragma unroll
  for (int a = 0; a < 4; ++a) {
    float4 c0 = f4sq(r[0 * 4 + a]), c1 = f4sq(r[1 * 4 + a]);
    float4 c2 = f4sq(r[2 * 4 + a]), c3 = f4sq(r[3 * 4 + a]);
    float4 c4 = f4sq(r[4 * 4 + a]), c5 = f4sq(r[5 * 4 + a]);
    float4 c6 = f4sq(r[6 * 4 + a]), c7 = f4sq(r[7 * 4 + a]);
    W[a] = f4add(f4add(f4add(c0, c1), f4add(c2, c3)),
                 f4add(f4add(c4, c5), f4add(c6, c7)));
  }
  float4 U0 = f4add(W[0], W[2]);
  float4 U1 = f4add(W[1], W[3]);
  float4 T = f4add(U0, U1);
  float s0 = T.x + T.z, s1 = T.y + T.w;
  return s0 + s1;
}

// Fused prologue, grid 1024 x 256. t1 via 4-lane-split np tree (verified
// bit-exact on HW in r18). prep unit gid<65536, t3/t3hl gid<4096,
// cnt gid<16384, out_loss gid==0.
__global__ __launch_bounds__(256, 2)
void k_pre(const float* __restrict__ x, const float* __restrict__ cb,
           float* __restrict__ outq, float* __restrict__ out_loss) {
  int gid = blockIdx.x * 256 + threadIdx.x;
  float* t1 = outq + OQ_T1;
  float* t3 = outq + OQ_T3;
  unsigned* t3hl = (unsigned*)(outq + OQ_T3HL);
  int* cnt = (int*)(outq + OQ_CNT);

  // ---- t1, 4-lane split (all 262144 threads; 4 lanes per row) ----
  {
    int row = gid >> 2, a = gid & 3;
    const float4* r4 = (const float4*)(x + (size_t)row * D_);
    float4 c0 = f4sq(r4[0 * 4 + a]), c1 = f4sq(r4[1 * 4 + a]);
    float4 c2 = f4sq(r4[2 * 4 + a]), c3 = f4sq(r4[3 * 4 + a]);
    float4 c4 = f4sq(r4[4 * 4 + a]), c5 = f4sq(r4[5 * 4 + a]);
    float4 c6 = f4sq(r4[6 * 4 + a]), c7 = f4sq(r4[7 * 4 + a]);
    float4 wv = f4add(f4add(f4add(c0, c1), f4add(c2, c3)),
                      f4add(f4add(c4, c5), f4add(c6, c7)));   // == W[a]
    int lb = (threadIdx.x & 63) & ~3;
    int sp = lb + (a | 2);
    float4 wp;
    wp.x = __shfl(wv.x, sp, 64); wp.y = __shfl(wv.y, sp, 64);
    wp.z = __shfl(wv.z, sp, 64); wp.w = __shfl(wv.w, sp, 64);
    float4 U = f4add(wv, wp);
    float4 u1;
    u1.x = __shfl(U.x, lb + 1, 64); u1.y = __shfl(U.y, lb + 1, 64);
    u1.z = __shfl(U.z, lb + 1, 64); u1.w = __shfl(U.w, lb + 1, 64);
    float4 T = f4add(U, u1);
    float res = (T.x + T.z) + (T.y + T.w);
    if (a == 0) t1[row] = res;
  }

  if (gid < KCODES) {
    float s = np_sumsq_row((const float4*)(cb + (size_t)gid * D_));
    t3[gid] = s;
    unsigned short h = bf16rne(s);
    unsigned short l = bf16rne(s - bf16tof(h));
    t3hl[gid] = (unsigned)h | ((unsigned)l << 16);
  }
  if (gid < 64 * NSUB * 16) cnt[gid] = 0;
  if (gid == 0) out_loss[0] = 0.f;

  if (gid < 64 * 1024) {
    // prep unit u: ch=u>>10, s=(u&1023)>>6 (kt=s>>1, ct=s&1), p=u&63
    // (kg=p>>5, nl=p&31); code = ch*64+ct*32+nl, k-off = (kt*2+kg)*8.
    int u = gid;
    int ch = u >> 10, r = u & 1023;
    int s2 = r >> 6, p = r & 63;
    int kt = s2 >> 1, ct = s2 & 1;
    int kg = p >> 5, nl = p & 31;
    int code = ch * 64 + ct * 32 + nl;
    const float* src = cb + (size_t)code * D_ + (kt * 2 + kg) * 8;
    bf16x8 h8;
#pragma unroll
    for (int e = 0; e < 8; ++e) h8[e] = (short)bf16rne(src[e]);
    *(bf16x8*)((char*)(outq + OQ_AH) + (size_t)u * 16) = h8;
  }
}

// Filter sweep (r16/r19-verified). Block = 256 thr = 4 waves; wave =
// 64 rows (xt=2) x 64-code chunks. Grid = 256 row-groups x 2 chunk-splits.
// acc = xh*eh - t3/2 (slab MFMA). Per iter: 16 ds_read_b128 -> 32 MFMA +
// 4 slab MFMA. cm store AFTER barrier; t3hl prefetched 1 iter ahead.
__global__ __launch_bounds__(256, 3)
void k_big(const float* __restrict__ x, const unsigned* __restrict__ t3hl,
           float* __restrict__ outq) {
  __shared__ char lds[2][16384];
  const int tid = threadIdx.x;
  const int lane = tid & 63;
  const int w = tid >> 6;
  const int kg = lane >> 5, nl = lane & 31;
  const int rb = blockIdx.x >> 1, cs = blockIdx.x & 1;
  const int row0 = rb * 256 + w * 64;

  const char* AhB = (const char*)(outq + OQ_AH);
  float* cm = outq;   // [64][65536]

  // x-hi fragments: lane holds row row0+xt*32+nl, k = (kt*2+kg)*8 + e
  bf16x8 xh[2][8];
#pragma unroll
  for (int xt = 0; xt < 2; ++xt)
#pragma unroll
    for (int kt = 0; kt < 8; ++kt) {
      const float* src =
          x + (size_t)(row0 + xt * 32 + nl) * D_ + (kt * 2 + kg) * 8;
      float f[8];
      *(float4*)(f) = *(const float4*)(src);
      *(float4*)(f + 4) = *(const float4*)(src + 4);
      bf16x8 h;
#pragma unroll
      for (int e = 0; e < 8; ++e) h[e] = (short)bf16rne(f[e]);
      xh[xt][kt] = h;
    }

  // B frag for t3 slab: k=0,1 hold -0.5 (kg==0 lanes)
  bf16x8 bneg = 0;
  if (kg == 0) { bneg[0] = (short)0xBF00; bneg[1] = (short)0xBF00; }

#define STAGE(c, buf)                                                         \
  {                                                                           \
    const char* sAh = AhB + (size_t)(c) * 16384;                              \
    _Pragma("unroll")                                                         \
    for (int i4 = 0; i4 < 4; ++i4) {                                          \
      int ub = i4 * 256 + w * 64;                                             \
      gload_lds16(sAh + (size_t)(ub + lane) * 16, (buf) + ub * 16);           \
    }                                                                         \
  }

  STAGE(cs * 32 + 0, lds[0]);
  unsigned v0 = t3hl[(cs * 32) * 64 + nl];
  unsigned v1 = t3hl[(cs * 32) * 64 + 32 + nl];
  __syncthreads();

  int b = 0;
  for (int it = 0; it < 32; ++it) {
    int ch = cs * 32 + it;
    char* cur = lds[b];
    if (it < 31) STAGE(ch + 1, lds[b ^ 1]);

    unsigned nv0 = 0, nv1 = 0;
    if (it < 31) {
      nv0 = t3hl[(ch + 1) * 64 + nl];
      nv1 = t3hl[(ch + 1) * 64 + 32 + nl];
    }

    bf16x8 s0 = 0, s1 = 0;
    if (kg == 0) {
      s0[0] = (short)(v0 & 0xFFFFu); s0[1] = (short)(v0 >> 16);
      s1[0] = (short)(v1 & 0xFFFFu); s1[1] = (short)(v1 >> 16);
    }

    f32x16 a00 = 0, a01 = 0, a10 = 0, a11 = 0;
    a00 = __builtin_amdgcn_mfma_f32_32x32x16_bf16(s0, bneg, a00, 0, 0, 0);
    a01 = __builtin_amdgcn_mfma_f32_32x32x16_bf16(s0, bneg, a01, 0, 0, 0);
    a10 = __builtin_amdgcn_mfma_f32_32x32x16_bf16(s1, bneg, a10, 0, 0, 0);
    a11 = __builtin_amdgcn_mfma_f32_32x32x16_bf16(s1, bneg, a11, 0, 0, 0);
#pragma unroll
    for (int kt = 0; kt < 8; ++kt) {
      bf16x8 e0 = *(const bf16x8*)(cur + ((kt * 2 + 0) * 64 + lane) * 16);
      bf16x8 e1 = *(const bf16x8*)(cur + ((kt * 2 + 1) * 64 + lane) * 16);
      a00 = __builtin_amdgcn_mfma_f32_32x32x16_bf16(e0, xh[0][kt], a00, 0, 0, 0);
      a01 = __builtin_amdgcn_mfma_f32_32x32x16_bf16(e0, xh[1][kt], a01, 0, 0, 0);
      a10 = __builtin_amdgcn_mfma_f32_32x32x16_bf16(e1, xh[0][kt], a10, 0, 0, 0);
      a11 = __builtin_amdgcn_mfma_f32_32x32x16_bf16(e1, xh[1][kt], a11, 0, 0, 0);
    }

    float m0 = -3.4e38f, m1 = -3.4e38f;
#pragma unroll
    for (int e = 0; e < 16; ++e) {
      m0 = fmaxf(m0, fmaxf(a00[e], a10[e]));   // xt0 rows
      m1 = fmaxf(m1, fmaxf(a01[e], a11[e]));   // xt1 rows
    }
    m0 = fmaxf(m0, __shfl_xor(m0, 32, 64));
    m1 = fmaxf(m1, __shfl_xor(m1, 32, 64));
    float mv = (kg == 0) ? m0 : m1;            // lanes 0-31: xt0, 32-63: xt1
    size_t caddr = (size_t)ch * MROWS + row0 + kg * 32 + nl;

    __syncthreads();
    cm[caddr] = mv;     // store after barrier: drains at NEXT barrier
    v0 = nv0; v1 = nv1;
    b ^= 1;
  }
#undef STAGE
}

// Candidate select, tile form. Sub-bucketed counters (round 7 verified).
__global__ __launch_bounds__(256, 4)
void k_cand(const float* __restrict__ cm, int* __restrict__ cnt,
            int* __restrict__ pairs, unsigned long long* __restrict__ keys,
            float dlt) {
  __shared__ float wmax[4][64];
  __shared__ float thrs[64];
  const int tid = threadIdx.x, lane = tid & 63, w = tid >> 6;
  const int r = blockIdx.x * 64 + lane;
  const int sub = blockIdx.x & (NSUB - 1);
  float v[16];
#pragma unroll
  for (int i = 0; i < 16; ++i) v[i] = cm[(size_t)(w * 16 + i) * MROWS + r];
  float m = v[0];
#pragma unroll
  for (int i = 1; i < 16; ++i) m = fmaxf(m, v[i]);
  wmax[w][lane] = m;
  __syncthreads();
  if (w == 0) {
    float A = fmaxf(fmaxf(wmax[0][lane], wmax[1][lane]),
                    fmaxf(wmax[2][lane], wmax[3][lane]));
    thrs[lane] = A - dlt;
    keys[r] = ~0ull;
  }
  __syncthreads();
  float thr = thrs[lane];
#pragma unroll
  for (int i = 0; i < 16; ++i) {
    if (v[i] >= thr) {
      int ch = w * 16 + i;
      int slot = ch * NSUB + sub;
      int s = atomicAdd(cnt + slot * 16, 1);
      if (s < SUBCAP) pairs[slot * SUBCAP + s] = r;
    }
  }
}

// np-bit-exact rescore. Block = (chunk ch, sub-bucket).
__global__ __launch_bounds__(256, 4)
void k_exact(const float* __restrict__ x, const float* __restrict__ cb,
             const int* __restrict__ cnt, const int* __restrict__ pairs,
             const float* __restrict__ t1, const float* __restrict__ t3,
             unsigned long long* __restrict__ keys) {
  __shared__ float elds[32 * 65 * 4];
  __shared__ float xlds[4][D_];
  int ch = blockIdx.x >> 4, sub = blockIdx.x & (NSUB - 1);
  int tid = threadIdx.x, lane = tid & 63, wid = tid >> 6;
#pragma unroll
  for (int it2 = 0; it2 < 8; ++it2) {
    int u = it2 * 256 + tid;        // 0..2047
    int c = u >> 5, d4 = u & 31;
    float4 v = *(const float4*)(cb + ((size_t)ch * 64 + c) * D_ + d4 * 4);
    *(float4*)(elds + (d4 * 65 + c) * 4) = v;
  }
  float t3v = t3[ch * 64 + lane];
  __syncthreads();
  int slot = ch * NSUB + sub;
  int n = cnt[slot * 16]; if (n > SUBCAP) n = SUBCAP;
  const int* lst = pairs + slot * SUBCAP;
  for (int idx = wid; idx < n; idx += 4) {
    int row = lst[idx];
    *(float2*)(&xlds[wid][lane * 2]) = *(const float2*)(x + (size_t)row * D_ + lane * 2);
    asm volatile("s_waitcnt lgkmcnt(0)" ::: "memory");
    float acc = 0.f;
    float t1r = t1[row];
#pragma unroll 8
    for (int d4 = 0; d4 < 32; ++d4) {
      float4 xv = *(const float4*)(&xlds[wid][d4 * 4]);
      float4 ev = *(const float4*)(elds + (d4 * 65 + lane) * 4);
      acc = __builtin_fmaf(xv.x, ev.x, acc);
      acc = __builtin_fmaf(xv.y, ev.y, acc);
      acc = __builtin_fmaf(xv.z, ev.z, acc);
      acc = __builtin_fmaf(xv.w, ev.w, acc);
    }
    float s = __builtin_fmaf(-2.f, acc, t1r) + t3v;
    unsigned u32 = __float_as_uint(s);
    u32 = u32 ^ (unsigned)(((int)u32 >> 31) | 0x80000000);
    unsigned long long key =
        ((unsigned long long)u32 << 12) | (unsigned)(ch * 64 + lane);
#pragma unroll
    for (int off = 1; off < 64; off <<= 1) {
      unsigned long long o = __shfl_xor(key, off, 64);
      key = o < key ? o : key;
    }
    if (lane == 0) atomicMin(keys + row, key);
  }
}

// keys -> token + gather quantized + per-block MSE partials (no fences,
// no cross-block protocol -- r18 lesson). keys live in d_ws.
__global__ __launch_bounds__(256, 8)
void k_gather(const float* __restrict__ x, const float* __restrict__ cb,
              const unsigned long long* __restrict__ keys,
              float* __restrict__ tok_f, float* __restrict__ outq,
              float* __restrict__ partial) {
  int idx = blockIdx.x * 256 + threadIdx.x;
  int row = idx >> 5;
  int d4 = idx & 31;
  int t = (int)(keys[row] & 0xFFFull);
  if (d4 == 0) tok_f[row] = (float)t;
  float4 q = ((const float4*)(cb + (size_t)t * D_))[d4];
  float4 xv = ((const float4*)x)[idx];
  ((float4*)outq)[idx] = q;
  float dx = q.x - xv.x, dy = q.y - xv.y, dz = q.z - xv.z, dw = q.w - xv.w;
  float s = dx * dx + dy * dy + dz * dz + dw * dw;
#pragma unroll
  for (int off = 1; off < 64; off <<= 1) s += __shfl_xor(s, off, 64);
  __shared__ float red[4];
  int lane = threadIdx.x & 63, w = threadIdx.x >> 6;
  if (lane == 0) red[w] = s;
  __syncthreads();
  if (threadIdx.x == 0)
    partial[blockIdx.x] = red[0] + red[1] + red[2] + red[3];
}

// 32 blocks x 256 partials each; one atomicAdd per block into out_loss
// (zeroed by k_pre). Verified r13-r19.
__global__ __launch_bounds__(256, 1)
void k_loss(const float* __restrict__ partial, float* __restrict__ out_loss,
            float scale) {
  int i = blockIdx.x * 256 + threadIdx.x;
  float s = partial[i];
#pragma unroll
  for (int off = 1; off < 64; off <<= 1) s += __shfl_xor(s, off, 64);
  __shared__ float red[4];
  int lane = threadIdx.x & 63, w = threadIdx.x >> 6;
  if (lane == 0) red[w] = s;
  __syncthreads();
  if (threadIdx.x == 0)
    atomicAdd(out_loss, (red[0] + red[1] + red[2] + red[3]) * scale);
}

extern "C" void kernel_launch(void* const* d_in, const int* in_sizes, int n_in,
                              void* d_out, int out_size, void* d_ws, size_t ws_size,
                              hipStream_t stream) {
  const float* x = (const float*)d_in[0];
  const float* cb = (const float*)d_in[1];

  float* out_tok = (float*)d_out;
  float* outq = (float*)d_out + MROWS;
  float* out_loss = (float*)d_out + MROWS + (size_t)MROWS * D_;

  // ws: keys u64[65536] (512KB) | part f32[8192] (32KB)
  unsigned long long* keys = (unsigned long long*)d_ws;
  float* part = (float*)((char*)d_ws + 524288);

  float* t3 = outq + OQ_T3;
  float* t1 = outq + OQ_T1;
  unsigned* t3hl = (unsigned*)(outq + OQ_T3HL);
  int* cnt = (int*)(outq + OQ_CNT);
  int* pairs = (int*)(outq + OQ_PAIRS);

  k_pre<<<1024, 256, 0, stream>>>(x, cb, outq, out_loss);
  k_big<<<(MROWS / 256) * 2, 256, 0, stream>>>(x, t3hl, outq);
  k_cand<<<MROWS / 64, 256, 0, stream>>>(outq, cnt, pairs, keys, 8e-3f);
  k_exact<<<64 * NSUB, 256, 0, stream>>>(x, cb, cnt, pairs, t1, t3, keys);
  const int gB = (MROWS * (D_ / 4)) / 256;   // 8192
  k_gather<<<gB, 256, 0, stream>>>(x, cb, keys, out_tok, outq, part);
  k_loss<<<32, 256, 0, stream>>>(part, out_loss,
                                 1.5f / (float)((size_t)MROWS * D_));
}